// Round 3
// baseline (605.892 us; speedup 1.0000x reference)
//
#include <hip/hip_runtime.h>
#include <hip/hip_bf16.h>
#include <type_traits>
#include <stdint.h>

#define AS1 __attribute__((address_space(1)))
#define AS3 __attribute__((address_space(3)))

typedef __attribute__((ext_vector_type(8))) short short8;
typedef __attribute__((ext_vector_type(4))) short short4v;
typedef __attribute__((ext_vector_type(4))) float floatx4;

#define B_DIM 8
#define S_DIM 4096
#define H_DIM 1024
#define M_DIM 1024

__device__ __forceinline__ float b2f(short s) {
  union { unsigned u; float f; } x;
  x.u = ((unsigned)(unsigned short)s) << 16;
  return x.f;
}
__device__ __forceinline__ short f2b(float f) {
  union { float f; unsigned u; } x;
  x.f = f;
  unsigned u = x.u;
  unsigned r = (u + 0x7fffu + ((u >> 16) & 1u)) >> 16;  // RNE
  return (short)(unsigned short)r;
}

__device__ __forceinline__ void async16(const void* g, void* l) {
  __builtin_amdgcn_global_load_lds((const AS1 void*)g, (AS3 void*)l, 16, 0, 0);
}

// ---------------- f32 -> bf16 convert ----------------
__global__ __launch_bounds__(256) void k_cvt(const float4* __restrict__ in,
                                             short4v* __restrict__ out, int n4) {
  const int stride = gridDim.x * 256;
  for (int i = blockIdx.x * 256 + threadIdx.x; i < n4; i += stride) {
    float4 v = in[i];
    short4v o = { f2b(v.x), f2b(v.y), f2b(v.z), f2b(v.w) };
    out[i] = o;
  }
}

// ---------------- GEMM: C[r][n] = sum_k A[r][k] * Bw[n][k] (+bias[n]) ----------------
// AMODE 0: direct rows. 1: memory-gather rows (idx = m*4095/1023). 2: concat(A,A2), K=2048.
// EPI 0: C[row*1024 + n]. 1: transposed store mvT[b][n][m] (rows are b*1024+m).
template<int AMODE, int EPI, typename OutT>
__global__ __launch_bounds__(256, 2)
void k_gemm(const short* __restrict__ A, const short* __restrict__ A2,
            const short* __restrict__ Bw, const float* __restrict__ bias,
            OutT* __restrict__ C, int K, long sA, long sB, long sC)
{
  __shared__ __align__(16) short As[128 * 32];
  __shared__ __align__(16) short Bs[128 * 32];

  const int t = threadIdx.x;
  const int l = t & 63;
  const int w = t >> 6;
  const int wm = w >> 1, wn = w & 1;
  const int z = blockIdx.z;
  const int row0 = blockIdx.x * 128;
  const int col0 = blockIdx.y * 128;

  const short* Az = A + (size_t)z * sA;
  const short* Bz = Bw + (size_t)z * sB;

  // staging: chunk c in [0,512): row = c>>2, k-offset = (c&3)*8 ; iters c0=t, c1=t+256
  const int c0 = t, c1 = t + 256;
  const int ra0 = c0 >> 2, ra1 = c1 >> 2;
  const int ka0 = (c0 & 3) * 8, ka1 = (c1 & 3) * 8;

  const short *aP0, *aP1, *aQ0 = nullptr, *aQ1 = nullptr;
  if (AMODE == 0) {
    aP0 = Az + (size_t)(row0 + ra0) * K + ka0;
    aP1 = Az + (size_t)(row0 + ra1) * K + ka1;
  } else if (AMODE == 1) {
    const int r0 = row0 + ra0, r1 = row0 + ra1;
    const unsigned m0 = (unsigned)(r0 & (M_DIM - 1)), m1 = (unsigned)(r1 & (M_DIM - 1));
    const int g0 = (r0 >> 10) * S_DIM + (int)((m0 * 4095u) / 1023u);
    const int g1 = (r1 >> 10) * S_DIM + (int)((m1 * 4095u) / 1023u);
    aP0 = A + (size_t)g0 * H_DIM + ka0;
    aP1 = A + (size_t)g1 * H_DIM + ka1;
  } else {
    const int r0 = row0 + ra0, r1 = row0 + ra1;
    aP0 = A  + (size_t)r0 * H_DIM + ka0;
    aP1 = A  + (size_t)r1 * H_DIM + ka1;
    aQ0 = A2 + (size_t)r0 * H_DIM + ka0 - 1024;
    aQ1 = A2 + (size_t)r1 * H_DIM + ka1 - 1024;
  }
  const short* bP0 = Bz + (size_t)(col0 + ra0) * K + ka0;
  const short* bP1 = Bz + (size_t)(col0 + ra1) * K + ka1;

  char* ldsA = (char*)As;
  char* ldsB = (char*)Bs;
  const int d0 = w * 1024;
  const int d1 = 4096 + w * 1024;

  floatx4 acc[4][4];
  #pragma unroll
  for (int i = 0; i < 4; ++i)
    #pragma unroll
    for (int j = 0; j < 4; ++j)
      acc[i][j] = (floatx4){0.f, 0.f, 0.f, 0.f};

  const int lr = l & 15;
  const int lk = (l >> 4) * 8;
  const int nk = K >> 5;

  for (int kt = 0; kt < nk; ++kt) {
    const int k0 = kt << 5;
    const short *pa0, *pa1;
    if (AMODE == 2) {
      if (k0 < 1024) { pa0 = aP0 + k0; pa1 = aP1 + k0; }
      else           { pa0 = aQ0 + k0; pa1 = aQ1 + k0; }
    } else { pa0 = aP0 + k0; pa1 = aP1 + k0; }
    async16(pa0, ldsA + d0);
    async16(pa1, ldsA + d1);
    async16(bP0 + k0, ldsB + d0);
    async16(bP1 + k0, ldsB + d1);
    __syncthreads();

    short8 af[4], bf[4];
    #pragma unroll
    for (int mi = 0; mi < 4; ++mi)
      af[mi] = *(const short8*)&As[(wm * 64 + mi * 16 + lr) * 32 + lk];
    #pragma unroll
    for (int ni = 0; ni < 4; ++ni)
      bf[ni] = *(const short8*)&Bs[(wn * 64 + ni * 16 + lr) * 32 + lk];
    #pragma unroll
    for (int mi = 0; mi < 4; ++mi)
      #pragma unroll
      for (int ni = 0; ni < 4; ++ni)
        acc[mi][ni] = __builtin_amdgcn_mfma_f32_16x16x32_bf16(af[mi], bf[ni], acc[mi][ni], 0, 0, 0);
    __syncthreads();
  }

  OutT* Cz = C + (size_t)z * sC;
  const int rbase = row0 + wm * 64;
  const int cbase = col0 + wn * 64;
  const int rsub = (l >> 4) * 4;
  #pragma unroll
  for (int ni = 0; ni < 4; ++ni) {
    const int colg = cbase + ni * 16 + lr;
    const float bvv = bias ? bias[colg] : 0.f;
    #pragma unroll
    for (int mi = 0; mi < 4; ++mi) {
      const int rg = rbase + mi * 16 + rsub;
      #pragma unroll
      for (int j = 0; j < 4; ++j) {
        const float v = acc[mi][ni][j] + bvv;
        if (EPI == 0) {
          const size_t o = (size_t)(rg + j) * 1024 + colg;
          if constexpr (std::is_same<OutT, float>::value) Cz[o] = v;
          else Cz[o] = f2b(v);
        } else {
          const int rr = rg + j;
          const int bb = rr >> 10, mm = rr & (M_DIM - 1);
          ((short*)C)[((size_t)bb * H_DIM + colg) * M_DIM + mm] = f2b(v);
        }
      }
    }
  }
}

// ---------------- row l2 normalize (in-place, bf16, row length 1024) ----------------
__global__ __launch_bounds__(256) void k_l2norm(short* __restrict__ x) {
  const size_t base = (size_t)blockIdx.x * 1024 + (size_t)threadIdx.x * 4;
  short4v v = *(short4v*)&x[base];
  const float f0 = b2f(v[0]), f1 = b2f(v[1]), f2 = b2f(v[2]), f3 = b2f(v[3]);
  float ss = f0 * f0 + f1 * f1 + f2 * f2 + f3 * f3;
  #pragma unroll
  for (int o = 32; o > 0; o >>= 1) ss += __shfl_xor(ss, o, 64);
  __shared__ float red[4];
  if ((threadIdx.x & 63) == 0) red[threadIdx.x >> 6] = ss;
  __syncthreads();
  const float tot = red[0] + red[1] + red[2] + red[3];
  const float s = 1.f / fmaxf(sqrtf(tot), 1e-12f);
  short4v o4 = { f2b(f0 * s), f2b(f1 * s), f2b(f2 * s), f2b(f3 * s) };
  *(short4v*)&x[base] = o4;
}

// ---------------- softmax over rows of 1024 (in-place bf16), 4 rows/block ----------------
__global__ __launch_bounds__(256) void k_softmax(short* __restrict__ sbuf) {
  const int w = threadIdx.x >> 6, l = threadIdx.x & 63;
  const size_t row = (size_t)blockIdx.x * 4 + w;
  short* p = sbuf + row * 1024 + l * 16;
  short8 v0 = *(short8*)p;
  short8 v1 = *(short8*)(p + 8);
  float f[16];
  #pragma unroll
  for (int i = 0; i < 8; ++i) { f[i] = b2f(v0[i]); f[8 + i] = b2f(v1[i]); }
  float mx = f[0];
  #pragma unroll
  for (int i = 1; i < 16; ++i) mx = fmaxf(mx, f[i]);
  #pragma unroll
  for (int o = 32; o > 0; o >>= 1) mx = fmaxf(mx, __shfl_xor(mx, o, 64));
  float s = 0.f;
  #pragma unroll
  for (int i = 0; i < 16; ++i) { f[i] = __expf(f[i] - mx); s += f[i]; }
  #pragma unroll
  for (int o = 32; o > 0; o >>= 1) s += __shfl_xor(s, o, 64);
  const float inv = 1.f / s;
  #pragma unroll
  for (int i = 0; i < 8; ++i) { v0[i] = f2b(f[i] * inv); v1[i] = f2b(f[8 + i] * inv); }
  *(short8*)p = v0;
  *(short8*)(p + 8) = v1;
}

extern "C" void kernel_launch(void* const* d_in, const int* in_sizes, int n_in,
                              void* d_out, int out_size, void* d_ws, size_t ws_size,
                              hipStream_t stream)
{
  const float* hid = (const float*)d_in[0];
  const float* Wq  = (const float*)d_in[1];
  const float* bq  = (const float*)d_in[2];
  const float* Wk  = (const float*)d_in[3];
  const float* bk  = (const float*)d_in[4];
  const float* Wv  = (const float*)d_in[5];
  const float* bv  = (const float*)d_in[6];
  const float* Wo  = (const float*)d_in[7];
  const float* bo  = (const float*)d_in[8];

  char* ws = (char*)d_ws;
  short* hb  = (short*)(ws);                          // 64 MiB  bf16 hidden
  short* qb  = (short*)(ws + (size_t)67108864);       // 64 MiB  bf16 q (later: retrieved)
  short* knb = (short*)(ws + (size_t)134217728);      // 16 MiB  bf16 normalized keys
  short* mvT = (short*)(ws + (size_t)150994944);      // 16 MiB  bf16 V transposed [b][h][m]
  short* wqb = (short*)(ws + (size_t)167772160);      // 2 MiB
  short* wkb = (short*)(ws + (size_t)169869312);      // 2 MiB
  short* wvb = (short*)(ws + (size_t)171966464);      // 2 MiB
  short* wob = (short*)(ws + (size_t)174063616);      // 4 MiB
  short* sb  = (short*)d_out;                         // scores/attn scratch inside d_out
  short* rb  = qb;                                    // retrieved aliases qb (qb dead by then)
  float* out = (float*)d_out;

  // converts
  k_cvt<<<4096, 256, 0, stream>>>((const float4*)hid, (short4v*)hb, 33554432 / 4);
  k_cvt<<<256, 256, 0, stream>>>((const float4*)Wq, (short4v*)wqb, 1048576 / 4);
  k_cvt<<<256, 256, 0, stream>>>((const float4*)Wk, (short4v*)wkb, 1048576 / 4);
  k_cvt<<<256, 256, 0, stream>>>((const float4*)Wv, (short4v*)wvb, 1048576 / 4);
  k_cvt<<<512, 256, 0, stream>>>((const float4*)Wo, (short4v*)wob, 2097152 / 4);

  dim3 blk(256, 1, 1);
  // Q projection: qb = hb @ Wq^T + bq
  k_gemm<0, 0, short><<<dim3(256, 8, 1), blk, 0, stream>>>(hb, nullptr, wqb, bq, qb, 1024, 0, 0, 0);
  // K projection (gathered rows): knb = init @ Wk^T + bk
  k_gemm<1, 0, short><<<dim3(64, 8, 1), blk, 0, stream>>>(hb, nullptr, wkb, bk, knb, 1024, 0, 0, 0);
  // V projection (gathered rows, transposed out): mvT[b][h][m]
  k_gemm<1, 1, short><<<dim3(64, 8, 1), blk, 0, stream>>>(hb, nullptr, wvb, bv, mvT, 1024, 0, 0, 0);
  // l2 normalize q and k rows (in place)
  k_l2norm<<<32768, 256, 0, stream>>>(qb);
  k_l2norm<<<8192, 256, 0, stream>>>(knb);
  // scores: sb[b][s][m] = qn[b][s] . kn[b][m]   (batched over z)
  k_gemm<0, 0, short><<<dim3(32, 8, 8), blk, 0, stream>>>(qb, nullptr, knb, nullptr, sb, 1024,
      (long)S_DIM * H_DIM, (long)M_DIM * H_DIM, (long)S_DIM * M_DIM);
  // softmax rows
  k_softmax<<<8192, 256, 0, stream>>>(sb);
  // retrieved: rb[b][s][h] = attn[b][s] . mvT[b][h]
  k_gemm<0, 0, short><<<dim3(32, 8, 8), blk, 0, stream>>>(sb, nullptr, mvT, nullptr, rb, 1024,
      (long)S_DIM * M_DIM, (long)H_DIM * M_DIM, (long)S_DIM * H_DIM);
  // output: out = concat(hb, rb) @ Wo^T + bo   (f32 out)
  k_gemm<2, 0, float><<<dim3(256, 8, 1), blk, 0, stream>>>(hb, rb, wob, bo, out, 2048, 0, 0, 0);
}

// Round 4
// 566.264 us; speedup vs baseline: 1.0700x; 1.0700x over previous
//
#include <hip/hip_runtime.h>
#include <hip/hip_bf16.h>
#include <type_traits>
#include <stdint.h>

#define AS1 __attribute__((address_space(1)))
#define AS3 __attribute__((address_space(3)))

typedef __attribute__((ext_vector_type(8))) short short8;
typedef __attribute__((ext_vector_type(4))) short short4v;
typedef __attribute__((ext_vector_type(4))) float floatx4;

#define B_DIM 8
#define S_DIM 4096
#define H_DIM 1024
#define M_DIM 1024

__device__ __forceinline__ float b2f(short s) {
  union { unsigned u; float f; } x;
  x.u = ((unsigned)(unsigned short)s) << 16;
  return x.f;
}
__device__ __forceinline__ short f2b(float f) {
  union { float f; unsigned u; } x;
  x.f = f;
  unsigned u = x.u;
  unsigned r = (u + 0x7fffu + ((u >> 16) & 1u)) >> 16;  // RNE
  return (short)(unsigned short)r;
}

__device__ __forceinline__ void barrier_raw() {
  asm volatile("" ::: "memory");
  __builtin_amdgcn_s_barrier();
  asm volatile("" ::: "memory");
}
#define VMCNT(N) asm volatile("s_waitcnt vmcnt(" #N ")" ::: "memory")

__device__ __forceinline__ void async16(const void* g, void* l) {
  __builtin_amdgcn_global_load_lds((const AS1 void*)g, (AS3 void*)l, 16, 0, 0);
}

// ---------------- f32 -> bf16 convert ----------------
__global__ __launch_bounds__(256) void k_cvt(const float4* __restrict__ in,
                                             short4v* __restrict__ out, int n4) {
  const int stride = gridDim.x * 256;
  for (int i = blockIdx.x * 256 + threadIdx.x; i < n4; i += stride) {
    float4 v = in[i];
    short4v o = { f2b(v.x), f2b(v.y), f2b(v.z), f2b(v.w) };
    out[i] = o;
  }
}

// ============ 256x256 8-phase GEMM (T1+T2+T3/T4+T5) ============
// C[r][n] = sum_k A[r][k] * Bw[n][k] (+bias[n]); N fixed at 1024 col stride.
// AMODE 0: A direct, K-stride K. AMODE 2: concat(A, A2), each K-stride 1024, K=2048.
template<int AMODE, bool HAS_BIAS, typename OutT>
__global__ __launch_bounds__(512, 2)
void k_gemm256(const short* __restrict__ A, const short* __restrict__ A2,
               const short* __restrict__ Bw, const float* __restrict__ bias,
               OutT* __restrict__ C, int K, long sA, long sB, long sC)
{
  // [buf][A=0/B=1][256 rows][64 shorts]; row = 128B, XOR-swizzled by ((row&7)<<4)
  __shared__ __align__(16) short lds[2][2][256 * 64];

  const int t512 = threadIdx.x;
  const int l = t512 & 63;
  const int w = t512 >> 6;            // wave 0..7
  const int wm = w >> 2, wn = w & 3;  // 2M x 4N wave grid
  const int z = blockIdx.z;

  // XCD-aware bijective swizzle within z-plane (nwg % 8 == 0 for all launches)
  const int gx = gridDim.x;
  int id = blockIdx.y * gx + blockIdx.x;
  const int nwg = gx * gridDim.y;
  if ((nwg & 7) == 0) {
    const int q8 = nwg >> 3;
    id = (id & 7) * q8 + (id >> 3);
  }
  const int row0 = (id % gx) * 256;
  const int col0 = (id / gx) * 256;

  const short* Az = A + (size_t)z * sA;
  const short* Bz = Bw + (size_t)z * sB;

  // staging geometry: one round = 64 rows x 128B = 8KB = 512 threads x 16B
  const int rloc = t512 >> 3;              // row within round, 0..63
  const int slot = t512 & 7;               // 16B slot
  const int sw = slot ^ (rloc & 7);        // pre-swizzled source slot
  const int nt = K >> 6;                   // K-tiles of 64

  // ds_read geometry
  const int lr = l & 15;
  const int lkb = (l >> 4) << 4;           // 0,16,32,48 (bytes)
  const int aswz = (lr & 7) << 4;
  const int aRowByte = (wm * 128 + lr) * 128;
  const int bRowByte = (wn * 64 + lr) * 128;

  auto srcA = [&](int R, int tile) -> const char* {
    if constexpr (AMODE == 2) {
      const size_t row = (size_t)(row0 + R + rloc);
      if (tile < 16) return (const char*)A  + ((row * 1024 + (size_t)tile * 64) << 1) + (sw << 4);
      else           return (const char*)A2 + ((row * 1024 + (size_t)(tile - 16) * 64) << 1) + (sw << 4);
    } else {
      return (const char*)Az + (((size_t)(row0 + R + rloc) * K + (size_t)tile * 64) << 1) + (sw << 4);
    }
  };
  auto srcB = [&](int R, int tile) -> const char* {
    return (const char*)Bz + (((size_t)(col0 + R + rloc) * K + (size_t)tile * 64) << 1) + (sw << 4);
  };
  auto SA = [&](int buf, int R, int tile) {
    async16(srcA(R, tile), (char*)&lds[buf][0][0] + (size_t)(R + w * 8) * 128);
  };
  auto SB = [&](int buf, int R, int tile) {
    async16(srcB(R, tile), (char*)&lds[buf][1][0] + (size_t)(R + w * 8) * 128);
  };

  floatx4 acc[8][4];
  #pragma unroll
  for (int i = 0; i < 8; ++i)
    #pragma unroll
    for (int j = 0; j < 4; ++j)
      acc[i][j] = (floatx4){0.f, 0.f, 0.f, 0.f};

  // ---- prologue: tile0 full -> buf0; tile1 early (A-lo halves + B-lo) -> buf1 ----
  {
    const int t1 = (nt > 1) ? 1 : 0;
    SA(0, 0, 0);  SA(0, 128, 0); SA(0, 64, 0); SA(0, 192, 0);
    SB(0, 0, 0);  SB(0, 64, 0);  SB(0, 128, 0); SB(0, 192, 0);
    SA(1, 0, t1); SA(1, 128, t1);
    SB(1, 0, t1); SB(1, 64, t1);
    VMCNT(4);
    barrier_raw();
  }

#define RD_A(Mh, ks)                                                              \
  {                                                                               \
    _Pragma("unroll")                                                             \
    for (int mi = 0; mi < 4; ++mi)                                                \
      af[mi] = *(const short8*)(ldsAb + aRowByte + (Mh) * 8192 + mi * 2048 +      \
                                ((((ks) * 64) + lkb) ^ aswz));                    \
  }
#define RD_B(ks)                                                                  \
  {                                                                               \
    _Pragma("unroll")                                                             \
    for (int ni = 0; ni < 4; ++ni)                                                \
      bf[ni] = *(const short8*)(ldsBb + bRowByte + ni * 2048 +                    \
                                ((((ks) * 64) + lkb) ^ aswz));                    \
  }
#define PH_MFMA(Mh)                                                               \
  {                                                                               \
    __builtin_amdgcn_s_setprio(1);                                                \
    _Pragma("unroll")                                                             \
    for (int mi = 0; mi < 4; ++mi)                                                \
      _Pragma("unroll")                                                           \
      for (int ni = 0; ni < 4; ++ni)                                              \
        acc[(Mh) * 4 + mi][ni] = __builtin_amdgcn_mfma_f32_16x16x32_bf16(         \
            af[mi], bf[ni], acc[(Mh) * 4 + mi][ni], 0, 0, 0);                     \
    __builtin_amdgcn_s_setprio(0);                                                \
  }

  for (int t = 0; t < nt; ++t) {
    const int b = t & 1;
    const char* ldsAb = (const char*)&lds[b][0][0];
    const char* ldsBb = (const char*)&lds[b][1][0];
    const int tn  = (t + 1 < nt) ? t + 1 : nt - 1;
    const int tn2 = (t + 2 < nt) ? t + 2 : nt - 1;
    short8 af[4], bf[4];

    // ---- PH1: (Mh0, k0); stage A-hi halves of t+1 -> buf^1 ----
    RD_A(0, 0); RD_B(0);
    SA(b ^ 1, 64, tn); SA(b ^ 1, 192, tn);
    barrier_raw();
    PH_MFMA(0);
    barrier_raw();

    // ---- PH2: (Mh1, k0); stage B-hi of t+1 -> buf^1 ----
    RD_A(1, 0);
    SB(b ^ 1, 128, tn); SB(b ^ 1, 192, tn);
    barrier_raw();
    PH_MFMA(1);
    barrier_raw();

    // ---- PH3: (Mh0, k1); no stage ----
    RD_A(0, 1); RD_B(1);
    barrier_raw();
    PH_MFMA(0);
    barrier_raw();

    // ---- PH4: (Mh1, k1); stage A-lo halves + B-lo of t+2 -> buf (regions freed by PH3) ----
    RD_A(1, 1);
    SA(b, 0, tn2); SA(b, 128, tn2);
    SB(b, 0, tn2); SB(b, 64, tn2);
    barrier_raw();
    PH_MFMA(1);
    VMCNT(4);
    barrier_raw();
  }
#undef RD_A
#undef RD_B
#undef PH_MFMA

  VMCNT(0);  // drain leftover prefetches (LDS unused from here)

  OutT* Cz = C + (size_t)z * sC;
  const int rsub = (l >> 4) * 4;
  #pragma unroll
  for (int ni = 0; ni < 4; ++ni) {
    const int colg = col0 + wn * 64 + ni * 16 + lr;
    const float bvv = HAS_BIAS ? bias[colg] : 0.f;
    #pragma unroll
    for (int m = 0; m < 8; ++m) {
      const int rg = row0 + wm * 128 + (m >> 2) * 64 + (m & 3) * 16 + rsub;
      #pragma unroll
      for (int j = 0; j < 4; ++j) {
        const float v = acc[m][ni][j] + bvv;
        const size_t o = (size_t)(rg + j) * 1024 + colg;
        if constexpr (std::is_same<OutT, float>::value) Cz[o] = v;
        else Cz[o] = f2b(v);
      }
    }
  }
}

// ============ legacy 128x128 GEMM (kept for gathered K/V projections) ============
// AMODE 1: memory-gather rows (idx = m*4095/1023).
// EPI 0: C[row*1024 + n]. 1: transposed store mvT[b][n][m] (rows are b*1024+m).
template<int AMODE, int EPI, typename OutT>
__global__ __launch_bounds__(256, 2)
void k_gemm(const short* __restrict__ A, const short* __restrict__ A2,
            const short* __restrict__ Bw, const float* __restrict__ bias,
            OutT* __restrict__ C, int K, long sA, long sB, long sC)
{
  __shared__ __align__(16) short As[128 * 32];
  __shared__ __align__(16) short Bs[128 * 32];

  const int t = threadIdx.x;
  const int l = t & 63;
  const int w = t >> 6;
  const int wm = w >> 1, wn = w & 1;
  const int z = blockIdx.z;
  const int row0 = blockIdx.x * 128;
  const int col0 = blockIdx.y * 128;

  const short* Az = A + (size_t)z * sA;
  const short* Bz = Bw + (size_t)z * sB;

  const int c0 = t, c1 = t + 256;
  const int ra0 = c0 >> 2, ra1 = c1 >> 2;
  const int ka0 = (c0 & 3) * 8, ka1 = (c1 & 3) * 8;

  const short *aP0, *aP1;
  if (AMODE == 1) {
    const int r0 = row0 + ra0, r1 = row0 + ra1;
    const unsigned m0 = (unsigned)(r0 & (M_DIM - 1)), m1 = (unsigned)(r1 & (M_DIM - 1));
    const int g0 = (r0 >> 10) * S_DIM + (int)((m0 * 4095u) / 1023u);
    const int g1 = (r1 >> 10) * S_DIM + (int)((m1 * 4095u) / 1023u);
    aP0 = A + (size_t)g0 * H_DIM + ka0;
    aP1 = A + (size_t)g1 * H_DIM + ka1;
  } else {
    aP0 = Az + (size_t)(row0 + ra0) * K + ka0;
    aP1 = Az + (size_t)(row0 + ra1) * K + ka1;
  }
  const short* bP0 = Bz + (size_t)(col0 + ra0) * K + ka0;
  const short* bP1 = Bz + (size_t)(col0 + ra1) * K + ka1;

  char* ldsA = (char*)As;
  char* ldsB = (char*)Bs;
  const int d0 = w * 1024;
  const int d1 = 4096 + w * 1024;

  floatx4 acc[4][4];
  #pragma unroll
  for (int i = 0; i < 4; ++i)
    #pragma unroll
    for (int j = 0; j < 4; ++j)
      acc[i][j] = (floatx4){0.f, 0.f, 0.f, 0.f};

  const int lr = l & 15;
  const int lk = (l >> 4) * 8;
  const int nk = K >> 5;

  for (int kt = 0; kt < nk; ++kt) {
    const int k0 = kt << 5;
    async16(aP0 + k0, ldsA + d0);
    async16(aP1 + k0, ldsA + d1);
    async16(bP0 + k0, ldsB + d0);
    async16(bP1 + k0, ldsB + d1);
    __syncthreads();

    short8 af[4], bf[4];
    #pragma unroll
    for (int mi = 0; mi < 4; ++mi)
      af[mi] = *(const short8*)&As[(wm * 64 + mi * 16 + lr) * 32 + lk];
    #pragma unroll
    for (int ni = 0; ni < 4; ++ni)
      bf[ni] = *(const short8*)&Bs[(wn * 64 + ni * 16 + lr) * 32 + lk];
    #pragma unroll
    for (int mi = 0; mi < 4; ++mi)
      #pragma unroll
      for (int ni = 0; ni < 4; ++ni)
        acc[mi][ni] = __builtin_amdgcn_mfma_f32_16x16x32_bf16(af[mi], bf[ni], acc[mi][ni], 0, 0, 0);
    __syncthreads();
  }

  const int rbase = row0 + wm * 64;
  const int cbase = col0 + wn * 64;
  const int rsub = (l >> 4) * 4;
  #pragma unroll
  for (int ni = 0; ni < 4; ++ni) {
    const int colg = cbase + ni * 16 + lr;
    const float bvv = bias ? bias[colg] : 0.f;
    #pragma unroll
    for (int mi = 0; mi < 4; ++mi) {
      const int rg = rbase + mi * 16 + rsub;
      #pragma unroll
      for (int j = 0; j < 4; ++j) {
        const float v = acc[mi][ni][j] + bvv;
        if (EPI == 0) {
          const size_t o = (size_t)(rg + j) * 1024 + colg;
          ((short*)C)[o] = f2b(v);
        } else {
          const int rr = rg + j;
          const int bb = rr >> 10, mm = rr & (M_DIM - 1);
          ((short*)C)[((size_t)bb * H_DIM + colg) * M_DIM + mm] = f2b(v);
        }
      }
    }
  }
}

// ---------------- row l2 normalize (in-place, bf16, row length 1024) ----------------
__global__ __launch_bounds__(256) void k_l2norm(short* __restrict__ x) {
  const size_t base = (size_t)blockIdx.x * 1024 + (size_t)threadIdx.x * 4;
  short4v v = *(short4v*)&x[base];
  const float f0 = b2f(v[0]), f1 = b2f(v[1]), f2 = b2f(v[2]), f3 = b2f(v[3]);
  float ss = f0 * f0 + f1 * f1 + f2 * f2 + f3 * f3;
  #pragma unroll
  for (int o = 32; o > 0; o >>= 1) ss += __shfl_xor(ss, o, 64);
  __shared__ float red[4];
  if ((threadIdx.x & 63) == 0) red[threadIdx.x >> 6] = ss;
  __syncthreads();
  const float tot = red[0] + red[1] + red[2] + red[3];
  const float s = 1.f / fmaxf(sqrtf(tot), 1e-12f);
  short4v o4 = { f2b(f0 * s), f2b(f1 * s), f2b(f2 * s), f2b(f3 * s) };
  *(short4v*)&x[base] = o4;
}

// ---------------- softmax over rows of 1024 (in-place bf16), 4 rows/block ----------------
__global__ __launch_bounds__(256) void k_softmax(short* __restrict__ sbuf) {
  const int w = threadIdx.x >> 6, l = threadIdx.x & 63;
  const size_t row = (size_t)blockIdx.x * 4 + w;
  short* p = sbuf + row * 1024 + l * 16;
  short8 v0 = *(short8*)p;
  short8 v1 = *(short8*)(p + 8);
  float f[16];
  #pragma unroll
  for (int i = 0; i < 8; ++i) { f[i] = b2f(v0[i]); f[8 + i] = b2f(v1[i]); }
  float mx = f[0];
  #pragma unroll
  for (int i = 1; i < 16; ++i) mx = fmaxf(mx, f[i]);
  #pragma unroll
  for (int o = 32; o > 0; o >>= 1) mx = fmaxf(mx, __shfl_xor(mx, o, 64));
  float s = 0.f;
  #pragma unroll
  for (int i = 0; i < 16; ++i) { f[i] = __expf(f[i] - mx); s += f[i]; }
  #pragma unroll
  for (int o = 32; o > 0; o >>= 1) s += __shfl_xor(s, o, 64);
  const float inv = 1.f / s;
  #pragma unroll
  for (int i = 0; i < 8; ++i) { v0[i] = f2b(f[i] * inv); v1[i] = f2b(f[8 + i] * inv); }
  *(short8*)p = v0;
  *(short8*)(p + 8) = v1;
}

extern "C" void kernel_launch(void* const* d_in, const int* in_sizes, int n_in,
                              void* d_out, int out_size, void* d_ws, size_t ws_size,
                              hipStream_t stream)
{
  const float* hid = (const float*)d_in[0];
  const float* Wq  = (const float*)d_in[1];
  const float* bq  = (const float*)d_in[2];
  const float* Wk  = (const float*)d_in[3];
  const float* bk  = (const float*)d_in[4];
  const float* Wv  = (const float*)d_in[5];
  const float* bv  = (const float*)d_in[6];
  const float* Wo  = (const float*)d_in[7];
  const float* bo  = (const float*)d_in[8];

  char* ws = (char*)d_ws;
  short* hb  = (short*)(ws);                          // 64 MiB  bf16 hidden
  short* qb  = (short*)(ws + (size_t)67108864);       // 64 MiB  bf16 q (later: retrieved)
  short* knb = (short*)(ws + (size_t)134217728);      // 16 MiB  bf16 normalized keys
  short* mvT = (short*)(ws + (size_t)150994944);      // 16 MiB  bf16 V transposed [b][h][m]
  short* wqb = (short*)(ws + (size_t)167772160);      // 2 MiB
  short* wkb = (short*)(ws + (size_t)169869312);      // 2 MiB
  short* wvb = (short*)(ws + (size_t)171966464);      // 2 MiB
  short* wob = (short*)(ws + (size_t)174063616);      // 4 MiB
  short* sb  = (short*)d_out;                         // scores/attn scratch inside d_out
  short* rb  = qb;                                    // retrieved aliases qb (qb dead by then)
  float* out = (float*)d_out;

  // converts
  k_cvt<<<4096, 256, 0, stream>>>((const float4*)hid, (short4v*)hb, 33554432 / 4);
  k_cvt<<<256, 256, 0, stream>>>((const float4*)Wq, (short4v*)wqb, 1048576 / 4);
  k_cvt<<<256, 256, 0, stream>>>((const float4*)Wk, (short4v*)wkb, 1048576 / 4);
  k_cvt<<<256, 256, 0, stream>>>((const float4*)Wv, (short4v*)wvb, 1048576 / 4);
  k_cvt<<<512, 256, 0, stream>>>((const float4*)Wo, (short4v*)wob, 2097152 / 4);

  // Q projection: qb = hb @ Wq^T + bq   (256^2 8-phase)
  k_gemm256<0, true, short><<<dim3(128, 4, 1), 512, 0, stream>>>(hb, nullptr, wqb, bq, qb, 1024, 0, 0, 0);
  // K projection (gathered rows): knb = init @ Wk^T + bk
  k_gemm<1, 0, short><<<dim3(64, 8, 1), 256, 0, stream>>>(hb, nullptr, wkb, bk, knb, 1024, 0, 0, 0);
  // V projection (gathered rows, transposed out): mvT[b][h][m]
  k_gemm<1, 1, short><<<dim3(64, 8, 1), 256, 0, stream>>>(hb, nullptr, wvb, bv, mvT, 1024, 0, 0, 0);
  // l2 normalize q and k rows (in place)
  k_l2norm<<<32768, 256, 0, stream>>>(qb);
  k_l2norm<<<8192, 256, 0, stream>>>(knb);
  // scores: sb[b][s][m] = qn[b][s] . kn[b][m]   (batched over z)
  k_gemm256<0, false, short><<<dim3(16, 4, 8), 512, 0, stream>>>(qb, nullptr, knb, nullptr, sb, 1024,
      (long)S_DIM * H_DIM, (long)M_DIM * H_DIM, (long)S_DIM * M_DIM);
  // softmax rows
  k_softmax<<<8192, 256, 0, stream>>>(sb);
  // retrieved: rb[b][s][h] = attn[b][s] . mvT[b][h]
  k_gemm256<0, false, short><<<dim3(16, 4, 8), 512, 0, stream>>>(sb, nullptr, mvT, nullptr, rb, 1024,
      (long)S_DIM * M_DIM, (long)H_DIM * M_DIM, (long)S_DIM * H_DIM);
  // output: out = concat(hb, rb) @ Wo^T + bo   (f32 out)
  k_gemm256<2, true, float><<<dim3(128, 4, 1), 512, 0, stream>>>(hb, rb, wob, bo, out, 2048, 0, 0, 0);
}

// Round 5
// 551.291 us; speedup vs baseline: 1.0990x; 1.0272x over previous
//
#include <hip/hip_runtime.h>
#include <hip/hip_bf16.h>
#include <type_traits>
#include <stdint.h>

#define AS1 __attribute__((address_space(1)))
#define AS3 __attribute__((address_space(3)))

typedef __attribute__((ext_vector_type(8))) short short8;
typedef __attribute__((ext_vector_type(4))) short short4v;
typedef __attribute__((ext_vector_type(4))) float floatx4;

#define B_DIM 8
#define S_DIM 4096
#define H_DIM 1024
#define M_DIM 1024

__device__ __forceinline__ float b2f(short s) {
  union { unsigned u; float f; } x;
  x.u = ((unsigned)(unsigned short)s) << 16;
  return x.f;
}
__device__ __forceinline__ short f2b(float f) {
  union { float f; unsigned u; } x;
  x.f = f;
  unsigned u = x.u;
  unsigned r = (u + 0x7fffu + ((u >> 16) & 1u)) >> 16;  // RNE
  return (short)(unsigned short)r;
}

__device__ __forceinline__ void barrier_raw() {
  asm volatile("" ::: "memory");
  __builtin_amdgcn_s_barrier();
  asm volatile("" ::: "memory");
}
#define VMCNT(N) asm volatile("s_waitcnt vmcnt(" #N ")" ::: "memory")

__device__ __forceinline__ void async16(const void* g, void* l) {
  __builtin_amdgcn_global_load_lds((const AS1 void*)g, (AS3 void*)l, 16, 0, 0);
}

// ---------------- f32 -> bf16 convert ----------------
__global__ __launch_bounds__(256) void k_cvt(const float4* __restrict__ in,
                                             short4v* __restrict__ out, int n4) {
  const int stride = gridDim.x * 256;
  for (int i = blockIdx.x * 256 + threadIdx.x; i < n4; i += stride) {
    float4 v = in[i];
    short4v o = { f2b(v.x), f2b(v.y), f2b(v.z), f2b(v.w) };
    out[i] = o;
  }
}

// ============ 256x256 8-phase GEMM (T1+T2+T3/T4+T5) ============
// C[r][n] = sum_k A[r][k] * Bw[n][k] (+bias[n]); N fixed at 1024 col stride.
// AMODE 0: A direct, K-stride K. AMODE 2: concat(A, A2), each K-stride 1024, K=2048.
// Staging rotation: P(t)@PH1 = {A1,A3 of t+1}(2 calls); Q(t)@PH4 = {A0,A2,B0..B3 of t+2}(6).
// Waits: vmcnt(8) at PH1-end (P(t) needed by PH2(t+1)), vmcnt(8) at PH4-end (Q(t-1) by PH1(t+1)).
template<int AMODE, bool HAS_BIAS, typename OutT>
__global__ __launch_bounds__(512, 2)
void k_gemm256(const short* __restrict__ A, const short* __restrict__ A2,
               const short* __restrict__ Bw, const float* __restrict__ bias,
               OutT* __restrict__ C, int K, long sA, long sB, long sC)
{
  // [buf][A=0/B=1][256 rows][64 shorts]; row = 128B, XOR-swizzled by ((row&7)<<4)
  __shared__ __align__(16) short lds[2][2][256 * 64];

  const int t512 = threadIdx.x;
  const int l = t512 & 63;
  const int w = t512 >> 6;            // wave 0..7
  const int wm = w >> 2, wn = w & 3;  // 2M x 4N wave grid
  const int z = blockIdx.z;

  // XCD-aware bijective chunk swizzle, col-fastest within chunk (A-panel reuse).
  const int gx = gridDim.x, gy = gridDim.y;
  const int orig = blockIdx.y * gx + blockIdx.x;
  const int nwg = gx * gy;
  int s = orig;
  if ((nwg & 7) == 0) {
    const int q8 = nwg >> 3;
    s = (orig & 7) * q8 + (orig >> 3);
  }
  const int row0 = (s / gy) * 256;
  const int col0 = (s % gy) * 256;

  const short* Az = A + (size_t)z * sA;
  const short* Bz = Bw + (size_t)z * sB;

  // staging geometry: one call = 64 rows x 128B = 8KB = 512 threads x 16B
  const int rloc = t512 >> 3;              // row within call, 0..63
  const int slot = t512 & 7;               // 16B slot
  const int sw = slot ^ (rloc & 7);        // pre-swizzled source slot
  const int nt = K >> 6;                   // K-tiles of 64

  // ds_read geometry
  const int lr = l & 15;
  const int lkb = (l >> 4) << 4;           // 0,16,32,48 (bytes)
  const int aswz = (lr & 7) << 4;
  const int aRowByte = (wm * 128 + lr) * 128;
  const int bRowByte = (wn * 64 + lr) * 128;

  auto srcA = [&](int R, int tile) -> const char* {
    if constexpr (AMODE == 2) {
      const size_t row = (size_t)(row0 + R + rloc);
      if (tile < 16) return (const char*)A  + ((row * 1024 + (size_t)tile * 64) << 1) + (sw << 4);
      else           return (const char*)A2 + ((row * 1024 + (size_t)(tile - 16) * 64) << 1) + (sw << 4);
    } else {
      return (const char*)Az + (((size_t)(row0 + R + rloc) * K + (size_t)tile * 64) << 1) + (sw << 4);
    }
  };
  auto srcB = [&](int R, int tile) -> const char* {
    return (const char*)Bz + (((size_t)(col0 + R + rloc) * K + (size_t)tile * 64) << 1) + (sw << 4);
  };
  auto SA = [&](int buf, int R, int tile) {
    async16(srcA(R, tile), (char*)&lds[buf][0][0] + (size_t)(R + w * 8) * 128);
  };
  auto SB = [&](int buf, int R, int tile) {
    async16(srcB(R, tile), (char*)&lds[buf][1][0] + (size_t)(R + w * 8) * 128);
  };

  floatx4 acc[8][4];
  #pragma unroll
  for (int i = 0; i < 8; ++i)
    #pragma unroll
    for (int j = 0; j < 4; ++j)
      acc[i][j] = (floatx4){0.f, 0.f, 0.f, 0.f};

  // ---- prologue: tile0 full (8) -> buf0; Qpre = {A0,A2,B0..B3 of t1} (6) -> buf1 ----
  {
    const int t1 = (nt > 1) ? 1 : 0;
    SA(0, 0, 0);  SA(0, 64, 0); SA(0, 128, 0); SA(0, 192, 0);
    SB(0, 0, 0);  SB(0, 64, 0); SB(0, 128, 0); SB(0, 192, 0);
    SA(1, 0, t1); SA(1, 128, t1);
    SB(1, 0, t1); SB(1, 64, t1); SB(1, 128, t1); SB(1, 192, t1);
    VMCNT(6);
    barrier_raw();
  }

#define RD_A(Mh, ks)                                                              \
  {                                                                               \
    _Pragma("unroll")                                                             \
    for (int mi = 0; mi < 4; ++mi)                                                \
      af[mi] = *(const short8*)(ldsAb + aRowByte + (Mh) * 8192 + mi * 2048 +      \
                                ((((ks) * 64) + lkb) ^ aswz));                    \
  }
#define RD_B(ks)                                                                  \
  {                                                                               \
    _Pragma("unroll")                                                             \
    for (int ni = 0; ni < 4; ++ni)                                                \
      bf[ni] = *(const short8*)(ldsBb + bRowByte + ni * 2048 +                    \
                                ((((ks) * 64) + lkb) ^ aswz));                    \
  }
#define PH_MFMA(Mh)                                                               \
  {                                                                               \
    __builtin_amdgcn_s_setprio(1);                                                \
    _Pragma("unroll")                                                             \
    for (int mi = 0; mi < 4; ++mi)                                                \
      _Pragma("unroll")                                                           \
      for (int ni = 0; ni < 4; ++ni)                                              \
        acc[(Mh) * 4 + mi][ni] = __builtin_amdgcn_mfma_f32_16x16x32_bf16(         \
            af[mi], bf[ni], acc[(Mh) * 4 + mi][ni], 0, 0, 0);                     \
    __builtin_amdgcn_s_setprio(0);                                                \
  }

  for (int t = 0; t < nt; ++t) {
    const int b = t & 1;
    const char* ldsAb = (const char*)&lds[b][0][0];
    const char* ldsBb = (const char*)&lds[b][1][0];
    const int tn  = (t + 1 < nt) ? t + 1 : nt - 1;
    const int tn2 = (t + 2 < nt) ? t + 2 : nt - 1;
    short8 af[4], bf[4];

    // ---- PH1: (Mh0, k0); P(t): stage A1,A3 of t+1 -> buf^1 ----
    RD_A(0, 0); RD_B(0);
    SA(b ^ 1, 64, tn); SA(b ^ 1, 192, tn);
    barrier_raw();
    PH_MFMA(0);
    VMCNT(8);            // drains P(t-1) (+older): A1,A3 of tile t ready for... (and P(t) cover for PH2(t+1))
    barrier_raw();

    // ---- PH2: (Mh1, k0); no stage ----
    RD_A(1, 0);
    barrier_raw();
    PH_MFMA(1);
    barrier_raw();

    // ---- PH3: (Mh0, k1); no stage ----
    RD_A(0, 1); RD_B(1);
    barrier_raw();
    PH_MFMA(0);
    barrier_raw();

    // ---- PH4: (Mh1, k1); Q(t): stage A0,A2,B0..B3 of t+2 -> buf (regions freed by PH3) ----
    RD_A(1, 1);
    SA(b, 0, tn2); SA(b, 128, tn2);
    SB(b, 0, tn2); SB(b, 64, tn2); SB(b, 128, tn2); SB(b, 192, tn2);
    barrier_raw();
    PH_MFMA(1);
    VMCNT(8);            // drains Q(t-1) (+older): tile t+1's A0,A2,B* ready for PH1(t+1)
    barrier_raw();
  }
#undef RD_A
#undef RD_B
#undef PH_MFMA

  VMCNT(0);  // drain leftover prefetches (LDS unused from here)

  OutT* Cz = C + (size_t)z * sC;
  const int rsub = (l >> 4) * 4;
  #pragma unroll
  for (int ni = 0; ni < 4; ++ni) {
    const int colg = col0 + wn * 64 + ni * 16 + lr;
    const float bvv = HAS_BIAS ? bias[colg] : 0.f;
    #pragma unroll
    for (int m = 0; m < 8; ++m) {
      const int rg = row0 + wm * 128 + (m >> 2) * 64 + (m & 3) * 16 + rsub;
      #pragma unroll
      for (int j = 0; j < 4; ++j) {
        const float v = acc[m][ni][j] + bvv;
        const size_t o = (size_t)(rg + j) * 1024 + colg;
        if constexpr (std::is_same<OutT, float>::value) Cz[o] = v;
        else Cz[o] = f2b(v);
      }
    }
  }
}

// ============ legacy 128x128 GEMM (kept for gathered K/V projections) ============
// AMODE 1: memory-gather rows (idx = m*4095/1023).
// EPI 0: C[row*1024 + n]. 1: transposed store mvT[b][n][m] (rows are b*1024+m).
template<int AMODE, int EPI, typename OutT>
__global__ __launch_bounds__(256, 2)
void k_gemm(const short* __restrict__ A, const short* __restrict__ A2,
            const short* __restrict__ Bw, const float* __restrict__ bias,
            OutT* __restrict__ C, int K, long sA, long sB, long sC)
{
  __shared__ __align__(16) short As[128 * 32];
  __shared__ __align__(16) short Bs[128 * 32];

  const int t = threadIdx.x;
  const int l = t & 63;
  const int w = t >> 6;
  const int wm = w >> 1, wn = w & 1;
  const int z = blockIdx.z;
  const int row0 = blockIdx.x * 128;
  const int col0 = blockIdx.y * 128;

  const short* Az = A + (size_t)z * sA;
  const short* Bz = Bw + (size_t)z * sB;

  const int c0 = t, c1 = t + 256;
  const int ra0 = c0 >> 2, ra1 = c1 >> 2;
  const int ka0 = (c0 & 3) * 8, ka1 = (c1 & 3) * 8;

  const short *aP0, *aP1;
  if (AMODE == 1) {
    const int r0 = row0 + ra0, r1 = row0 + ra1;
    const unsigned m0 = (unsigned)(r0 & (M_DIM - 1)), m1 = (unsigned)(r1 & (M_DIM - 1));
    const int g0 = (r0 >> 10) * S_DIM + (int)((m0 * 4095u) / 1023u);
    const int g1 = (r1 >> 10) * S_DIM + (int)((m1 * 4095u) / 1023u);
    aP0 = A + (size_t)g0 * H_DIM + ka0;
    aP1 = A + (size_t)g1 * H_DIM + ka1;
  } else {
    aP0 = Az + (size_t)(row0 + ra0) * K + ka0;
    aP1 = Az + (size_t)(row0 + ra1) * K + ka1;
  }
  const short* bP0 = Bz + (size_t)(col0 + ra0) * K + ka0;
  const short* bP1 = Bz + (size_t)(col0 + ra1) * K + ka1;

  char* ldsA = (char*)As;
  char* ldsB = (char*)Bs;
  const int d0 = w * 1024;
  const int d1 = 4096 + w * 1024;

  floatx4 acc[4][4];
  #pragma unroll
  for (int i = 0; i < 4; ++i)
    #pragma unroll
    for (int j = 0; j < 4; ++j)
      acc[i][j] = (floatx4){0.f, 0.f, 0.f, 0.f};

  const int lr = l & 15;
  const int lk = (l >> 4) * 8;
  const int nk = K >> 5;

  for (int kt = 0; kt < nk; ++kt) {
    const int k0 = kt << 5;
    async16(aP0 + k0, ldsA + d0);
    async16(aP1 + k0, ldsA + d1);
    async16(bP0 + k0, ldsB + d0);
    async16(bP1 + k0, ldsB + d1);
    __syncthreads();

    short8 af[4], bf[4];
    #pragma unroll
    for (int mi = 0; mi < 4; ++mi)
      af[mi] = *(const short8*)&As[(wm * 64 + mi * 16 + lr) * 32 + lk];
    #pragma unroll
    for (int ni = 0; ni < 4; ++ni)
      bf[ni] = *(const short8*)&Bs[(wn * 64 + ni * 16 + lr) * 32 + lk];
    #pragma unroll
    for (int mi = 0; mi < 4; ++mi)
      #pragma unroll
      for (int ni = 0; ni < 4; ++ni)
        acc[mi][ni] = __builtin_amdgcn_mfma_f32_16x16x32_bf16(af[mi], bf[ni], acc[mi][ni], 0, 0, 0);
    __syncthreads();
  }

  const int rbase = row0 + wm * 64;
  const int cbase = col0 + wn * 64;
  const int rsub = (l >> 4) * 4;
  #pragma unroll
  for (int ni = 0; ni < 4; ++ni) {
    const int colg = cbase + ni * 16 + lr;
    const float bvv = bias ? bias[colg] : 0.f;
    #pragma unroll
    for (int mi = 0; mi < 4; ++mi) {
      const int rg = rbase + mi * 16 + rsub;
      #pragma unroll
      for (int j = 0; j < 4; ++j) {
        const float v = acc[mi][ni][j] + bvv;
        if (EPI == 0) {
          const size_t o = (size_t)(rg + j) * 1024 + colg;
          ((short*)C)[o] = f2b(v);
        } else {
          const int rr = rg + j;
          const int bb = rr >> 10, mm = rr & (M_DIM - 1);
          ((short*)C)[((size_t)bb * H_DIM + colg) * M_DIM + mm] = f2b(v);
        }
      }
    }
  }
}

// ---------------- row l2 normalize (in-place, bf16, row length 1024) ----------------
__global__ __launch_bounds__(256) void k_l2norm(short* __restrict__ x) {
  const size_t base = (size_t)blockIdx.x * 1024 + (size_t)threadIdx.x * 4;
  short4v v = *(short4v*)&x[base];
  const float f0 = b2f(v[0]), f1 = b2f(v[1]), f2 = b2f(v[2]), f3 = b2f(v[3]);
  float ss = f0 * f0 + f1 * f1 + f2 * f2 + f3 * f3;
  #pragma unroll
  for (int o = 32; o > 0; o >>= 1) ss += __shfl_xor(ss, o, 64);
  __shared__ float red[4];
  if ((threadIdx.x & 63) == 0) red[threadIdx.x >> 6] = ss;
  __syncthreads();
  const float tot = red[0] + red[1] + red[2] + red[3];
  const float s = 1.f / fmaxf(sqrtf(tot), 1e-12f);
  short4v o4 = { f2b(f0 * s), f2b(f1 * s), f2b(f2 * s), f2b(f3 * s) };
  *(short4v*)&x[base] = o4;
}

// ---------------- softmax over rows of 1024 (in-place bf16), 4 rows/block ----------------
__global__ __launch_bounds__(256) void k_softmax(short* __restrict__ sbuf) {
  const int w = threadIdx.x >> 6, l = threadIdx.x & 63;
  const size_t row = (size_t)blockIdx.x * 4 + w;
  short* p = sbuf + row * 1024 + l * 16;
  short8 v0 = *(short8*)p;
  short8 v1 = *(short8*)(p + 8);
  float f[16];
  #pragma unroll
  for (int i = 0; i < 8; ++i) { f[i] = b2f(v0[i]); f[8 + i] = b2f(v1[i]); }
  float mx = f[0];
  #pragma unroll
  for (int i = 1; i < 16; ++i) mx = fmaxf(mx, f[i]);
  #pragma unroll
  for (int o = 32; o > 0; o >>= 1) mx = fmaxf(mx, __shfl_xor(mx, o, 64));
  float s = 0.f;
  #pragma unroll
  for (int i = 0; i < 16; ++i) { f[i] = __expf(f[i] - mx); s += f[i]; }
  #pragma unroll
  for (int o = 32; o > 0; o >>= 1) s += __shfl_xor(s, o, 64);
  const float inv = 1.f / s;
  #pragma unroll
  for (int i = 0; i < 8; ++i) { v0[i] = f2b(f[i] * inv); v1[i] = f2b(f[8 + i] * inv); }
  *(short8*)p = v0;
  *(short8*)(p + 8) = v1;
}

extern "C" void kernel_launch(void* const* d_in, const int* in_sizes, int n_in,
                              void* d_out, int out_size, void* d_ws, size_t ws_size,
                              hipStream_t stream)
{
  const float* hid = (const float*)d_in[0];
  const float* Wq  = (const float*)d_in[1];
  const float* bq  = (const float*)d_in[2];
  const float* Wk  = (const float*)d_in[3];
  const float* bk  = (const float*)d_in[4];
  const float* Wv  = (const float*)d_in[5];
  const float* bv  = (const float*)d_in[6];
  const float* Wo  = (const float*)d_in[7];
  const float* bo  = (const float*)d_in[8];

  char* ws = (char*)d_ws;
  short* hb  = (short*)(ws);                          // 64 MiB  bf16 hidden
  short* qb  = (short*)(ws + (size_t)67108864);       // 64 MiB  bf16 q (later: retrieved)
  short* knb = (short*)(ws + (size_t)134217728);      // 16 MiB  bf16 normalized keys
  short* mvT = (short*)(ws + (size_t)150994944);      // 16 MiB  bf16 V transposed [b][h][m]
  short* wqb = (short*)(ws + (size_t)167772160);      // 2 MiB
  short* wkb = (short*)(ws + (size_t)169869312);      // 2 MiB
  short* wvb = (short*)(ws + (size_t)171966464);      // 2 MiB
  short* wob = (short*)(ws + (size_t)174063616);      // 4 MiB
  short* sb  = (short*)d_out;                         // scores/attn scratch inside d_out
  short* rb  = qb;                                    // retrieved aliases qb (qb dead by then)
  float* out = (float*)d_out;

  // converts
  k_cvt<<<4096, 256, 0, stream>>>((const float4*)hid, (short4v*)hb, 33554432 / 4);
  k_cvt<<<256, 256, 0, stream>>>((const float4*)Wq, (short4v*)wqb, 1048576 / 4);
  k_cvt<<<256, 256, 0, stream>>>((const float4*)Wk, (short4v*)wkb, 1048576 / 4);
  k_cvt<<<256, 256, 0, stream>>>((const float4*)Wv, (short4v*)wvb, 1048576 / 4);
  k_cvt<<<512, 256, 0, stream>>>((const float4*)Wo, (short4v*)wob, 2097152 / 4);

  // Q projection: qb = hb @ Wq^T + bq   (256^2 8-phase)
  k_gemm256<0, true, short><<<dim3(128, 4, 1), 512, 0, stream>>>(hb, nullptr, wqb, bq, qb, 1024, 0, 0, 0);
  // K projection (gathered rows): knb = init @ Wk^T + bk
  k_gemm<1, 0, short><<<dim3(64, 8, 1), 256, 0, stream>>>(hb, nullptr, wkb, bk, knb, 1024, 0, 0, 0);
  // V projection (gathered rows, transposed out): mvT[b][h][m]
  k_gemm<1, 1, short><<<dim3(64, 8, 1), 256, 0, stream>>>(hb, nullptr, wvb, bv, mvT, 1024, 0, 0, 0);
  // l2 normalize q and k rows (in place)
  k_l2norm<<<32768, 256, 0, stream>>>(qb);
  k_l2norm<<<8192, 256, 0, stream>>>(knb);
  // scores: sb[b][s][m] = qn[b][s] . kn[b][m]   (batched over z)
  k_gemm256<0, false, short><<<dim3(16, 4, 8), 512, 0, stream>>>(qb, nullptr, knb, nullptr, sb, 1024,
      (long)S_DIM * H_DIM, (long)M_DIM * H_DIM, (long)S_DIM * M_DIM);
  // softmax rows
  k_softmax<<<8192, 256, 0, stream>>>(sb);
  // retrieved: rb[b][s][h] = attn[b][s] . mvT[b][h]
  k_gemm256<0, false, short><<<dim3(16, 4, 8), 512, 0, stream>>>(sb, nullptr, mvT, nullptr, rb, 1024,
      (long)S_DIM * M_DIM, (long)H_DIM * M_DIM, (long)S_DIM * H_DIM);
  // output: out = concat(hb, rb) @ Wo^T + bo   (f32 out)
  k_gemm256<2, true, float><<<dim3(128, 4, 1), 512, 0, stream>>>(hb, rb, wob, bo, out, 2048, 0, 0, 0);
}